// Round 4
// baseline (239.858 us; speedup 1.0000x reference)
//
#include <hip/hip_runtime.h>

#define NT      2000
#define BATCH   4096
#define NODES   64
#define TBL_N   8192
#define JMAX    3.6f
#define TBLOCKS (TBL_N / 256)          // 32 table-builder blocks

// ---------------- MLP evaluation helper (build phase only) ----------------
__device__ __forceinline__ float mlp_rho(float j,
    const float* sW1, const float* sB1, const float* sW2,
    const float* sB2, const float* sW3, float b3v) {
    float h1[NODES];
#pragma unroll
    for (int k = 0; k < NODES; ++k)
        h1[k] = fmaxf(fmaf(j, sW1[k], sB1[k]), 0.0f);
    float rho = b3v;
    for (int nt = 0; nt < NODES; nt += 8) {
        float acc[8];
#pragma unroll
        for (int q = 0; q < 8; ++q) acc[q] = sB2[nt + q];
#pragma unroll
        for (int k = 0; k < NODES; ++k) {
            float a = h1[k];
#pragma unroll
            for (int q = 0; q < 8; ++q)
                acc[q] = fmaf(a, sW2[k * NODES + nt + q], acc[q]);
        }
#pragma unroll
        for (int q = 0; q < 8; ++q)
            rho = fmaf(fmaxf(acc[q], 0.0f), sW3[nt + q], rho);
    }
    return rho;
}

// ------ kernel 1: blocks [0,32) build rho table; blocks [32,..) fill time plane ------
__global__ __launch_bounds__(256) void prep(
    const float* __restrict__ W1, const float* __restrict__ b1,
    const float* __restrict__ W2, const float* __restrict__ b2,
    const float* __restrict__ W3, const float* __restrict__ b3,
    float2* __restrict__ tbl, float* __restrict__ out) {
    __shared__ float sW2[NODES * NODES];
    __shared__ float sW1[NODES], sB1[NODES], sB2[NODES], sW3[NODES];
    __shared__ float sB3;

    if (blockIdx.x < TBLOCKS) {
        for (int i = threadIdx.x; i < NODES * NODES; i += 256) sW2[i] = W2[i];
        if (threadIdx.x < NODES) {
            sW1[threadIdx.x] = W1[threadIdx.x];
            sB1[threadIdx.x] = b1[threadIdx.x];
            sB2[threadIdx.x] = b2[threadIdx.x];
            sW3[threadIdx.x] = W3[threadIdx.x];
        }
        if (threadIdx.x == 0) sB3 = b3[0];
        __syncthreads();

        int idx = blockIdx.x * 256 + threadIdx.x;
        const float h = JMAX / (float)TBL_N;
        float j0 = h * (float)idx;
        float v0 = mlp_rho(j0,     sW1, sB1, sW2, sB2, sW3, sB3);
        float v1 = mlp_rho(j0 + h, sW1, sB1, sW2, sB2, sW3, sB3);
        tbl[idx] = make_float2(v0, v1 - v0);
    } else {
        // time plane: out[3*B*NT + b*NT + t] = 0.1f * t
        int e = (blockIdx.x - TBLOCKS) * 256 + threadIdx.x;   // float4 index
        int t0 = (e * 4) % NT;                                // NT % 4 == 0
        float4 v = make_float4(0.1f * (float)t0, 0.1f * (float)(t0 + 1),
                               0.1f * (float)(t0 + 2), 0.1f * (float)(t0 + 3));
        reinterpret_cast<float4*>(out + 3 * (size_t)BATCH * NT)[e] = v;
    }
}

// ---------------- kernel 2: per-lane sequential simulation ----------------
__global__ __launch_bounds__(64, 1) void simulate(
    const float* __restrict__ Cv, const float* __restrict__ K,
    const float* __restrict__ jmin, const float2* __restrict__ tbl,
    float* __restrict__ out) {
    __shared__ float2 stbl[TBL_N];    // 64 KB
    const int l = threadIdx.x;
    for (int i = l; i < TBL_N / 2; i += 64)
        reinterpret_cast<float4*>(stbl)[i] =
            reinterpret_cast<const float4*>(tbl)[i];
    __syncthreads();

    const int b = blockIdx.x * 64 + l;
    const float cv = Cv[b];
    const float kk = K[b];
    const float jm = jmin[b];
    const float Qmin = 3.3068376f * powf(kk, 1.3333334f);
    const float cvDT = cv * 0.1f;
    const float invh = (float)TBL_N / JMAX;

    float* __restrict__ oT = out + (size_t)b * NT;
    float* __restrict__ oR = out + (size_t)BATCH * NT + (size_t)b * NT;
    float* __restrict__ oC = out + 2 * (size_t)BATCH * NT + (size_t)b * NT;

    oT[0] = 0.0f;
    oR[0] = 50.0f;
    oC[0] = 1e-3f;

    float res = 50.0f, thk = 0.0f, Q = 0.0f, jprev = 0.0f;

    // depth-4 prefetch pipeline; slots hold (v, dv, frac) for steps o=1..4.
    // res == 50 exactly for these steps => jcur_o = 0.00175*o exact.
    float v_[4], d_[4], f_[4];
#pragma unroll
    for (int t = 0; t < 4; ++t) {
        float x = (0.00175f * (float)(t + 1)) * invh;
        int ip = (int)x;
        f_[t] = x - (float)ip;
        float2 vd = stbl[ip];
        v_[t] = vd.x; d_[t] = vd.y;
    }

#pragma unroll 4
    for (int o = 1; o < NT; ++o) {
        const int s = (o - 1) & 3;                      // compile-time per unroll lane
        float BC   = 0.1f * (float)o;
        float den  = fmaf(0.14f, res, 1.0f);
        float jcur = (0.14f * BC) * __builtin_amdgcn_rcpf(den);
        float Qn   = fmaf(jcur, 0.1f, Q);

        // rho for THIS step (prefetched 4 steps ago)
        float rho = fmaf(f_[s], d_[s], v_[s]);

        // issue prefetch for step o+4 into the freed slot
        float jpred = fmaf(4.0f, jcur - jprev, jcur);
        jprev = jcur;
        float xp = fminf(fmaxf(jpred * invh, 0.0f), (float)(TBL_N - 2));
        int ip = (int)xp;
        f_[s] = xp - (float)ip;
        float2 vd = stbl[ip];
        v_[s] = vd.x; d_[s] = vd.y;

        float d1    = jcur - jm;
        float thk_l = fmaxf(fmaf(d1, cvDT, thk), 0.0f);         // _limit(..,0)
        float res_l = fmaxf(fmaf(d1, rho * cvDT, res), 50.0f);  // _limit(..,50)
        bool upd = Qn > Qmin;                                   // _tradeoff gate
        thk = upd ? thk_l : thk;
        res = upd ? res_l : res;
        Q = Qn;

        oT[o] = thk;
        oR[o] = res;
        oC[o] = jcur;
    }
}

extern "C" void kernel_launch(void* const* d_in, const int* in_sizes, int n_in,
                              void* d_out, int out_size, void* d_ws, size_t ws_size,
                              hipStream_t stream) {
    const float* Cv   = (const float*)d_in[0];
    const float* K    = (const float*)d_in[1];
    const float* jmin = (const float*)d_in[2];
    const float* W1   = (const float*)d_in[3];
    const float* b1   = (const float*)d_in[4];
    const float* W2   = (const float*)d_in[5];
    const float* b2   = (const float*)d_in[6];
    const float* W3   = (const float*)d_in[7];
    const float* b3   = (const float*)d_in[8];
    float* out = (float*)d_out;
    float2* tbl = (float2*)d_ws;   // TBL_N float2 = 64 KB scratch

    const int fill_blocks = (BATCH * NT / 4) / 256;   // 8000
    prep<<<TBLOCKS + fill_blocks, 256, 0, stream>>>(W1, b1, W2, b2, W3, b3, tbl, out);
    simulate<<<BATCH / 64, 64, 0, stream>>>(Cv, K, jmin, tbl, out);
}

// Round 5
// 224.099 us; speedup vs baseline: 1.0703x; 1.0703x over previous
//
#include <hip/hip_runtime.h>

#define NT      2000
#define BATCH   4096
#define NODES   64
#define TBL_N   8192
#define JMAX    3.6f
#define TBLOCKS (TBL_N / 256)

// ---------------- MLP evaluation helper (build phase only) ----------------
__device__ __forceinline__ float mlp_rho(float j,
    const float* sW1, const float* sB1, const float* sW2,
    const float* sB2, const float* sW3, float b3v) {
    float h1[NODES];
#pragma unroll
    for (int k = 0; k < NODES; ++k)
        h1[k] = fmaxf(fmaf(j, sW1[k], sB1[k]), 0.0f);
    float rho = b3v;
    for (int nt = 0; nt < NODES; nt += 8) {
        float acc[8];
#pragma unroll
        for (int q = 0; q < 8; ++q) acc[q] = sB2[nt + q];
#pragma unroll
        for (int k = 0; k < NODES; ++k) {
            float a = h1[k];
#pragma unroll
            for (int q = 0; q < 8; ++q)
                acc[q] = fmaf(a, sW2[k * NODES + nt + q], acc[q]);
        }
#pragma unroll
        for (int q = 0; q < 8; ++q)
            rho = fmaf(fmaxf(acc[q], 0.0f), sW3[nt + q], rho);
    }
    return rho;
}

// ------ kernel 1: blocks [0,32) build rho table; rest fill time plane ------
__global__ __launch_bounds__(256) void prep(
    const float* __restrict__ W1, const float* __restrict__ b1,
    const float* __restrict__ W2, const float* __restrict__ b2,
    const float* __restrict__ W3, const float* __restrict__ b3,
    float2* __restrict__ tbl, float* __restrict__ out) {
    __shared__ float sW2[NODES * NODES];
    __shared__ float sW1[NODES], sB1[NODES], sB2[NODES], sW3[NODES];
    __shared__ float sB3;

    if (blockIdx.x < TBLOCKS) {
        for (int i = threadIdx.x; i < NODES * NODES; i += 256) sW2[i] = W2[i];
        if (threadIdx.x < NODES) {
            sW1[threadIdx.x] = W1[threadIdx.x];
            sB1[threadIdx.x] = b1[threadIdx.x];
            sB2[threadIdx.x] = b2[threadIdx.x];
            sW3[threadIdx.x] = W3[threadIdx.x];
        }
        if (threadIdx.x == 0) sB3 = b3[0];
        __syncthreads();

        int idx = blockIdx.x * 256 + threadIdx.x;
        const float h = JMAX / (float)TBL_N;
        float j0 = h * (float)idx;
        float v0 = mlp_rho(j0,     sW1, sB1, sW2, sB2, sW3, sB3);
        float v1 = mlp_rho(j0 + h, sW1, sB1, sW2, sB2, sW3, sB3);
        tbl[idx] = make_float2(v0, v1 - v0);
    } else {
        int e = (blockIdx.x - TBLOCKS) * 256 + threadIdx.x;   // float4 index
        int t0 = (e * 4) % NT;                                // NT % 4 == 0
        float4 v = make_float4(0.1f * (float)t0, 0.1f * (float)(t0 + 1),
                               0.1f * (float)(t0 + 2), 0.1f * (float)(t0 + 3));
        reinterpret_cast<float4*>(out + 3 * (size_t)BATCH * NT)[e] = v;
    }
}

// one 4-step half: issue prefetch for steps OB+4..OB+7 into bank B,
// consume bank A for steps OB..OB+3.
#define HALF(AV, AD, AF, BV, BD, BF, GATED, OB)                             \
  {                                                                         \
    _Pragma("unroll")                                                       \
    for (int t = 0; t < 4; ++t) {                                           \
      float p = fmaf((float)(t + 5), dxe, xe);                              \
      p = fminf(fmaxf(p, 0.0f), (float)(TBL_N - 2));                        \
      int ip = (int)p;                                                      \
      BF[t] = p - (float)ip;                                                \
      float2 vd = stbl[ip];                                                 \
      BV[t] = vd.x; BD[t] = vd.y;                                           \
    }                                                                       \
    float x2s = 0.0f, x3s = 0.0f;                                           \
    _Pragma("unroll")                                                       \
    for (int t = 0; t < 4; ++t) {                                           \
      int o = (OB) + t;                                                     \
      float BC  = 0.1f * (float)o;                                          \
      float den = fmaf(0.14f, res, 1.0f);                                   \
      float jc  = (0.14f * BC) * __builtin_amdgcn_rcpf(den);                \
      float rho = fmaf(AF[t], AD[t], AV[t]);                                \
      float d1  = jc - jm;                                                  \
      float tn  = fmaxf(fmaf(d1, cvDT, thk), 0.0f);                         \
      float rn  = fmaxf(fmaf(d1, rho * cvDT, res), 50.0f);                  \
      if (GATED) {                                                          \
        bool g = (o >= nc);                                                 \
        thk = g ? tn : thk;  res = g ? rn : res;                            \
      } else { thk = tn; res = rn; }                                        \
      oT[o] = thk; oR[o] = res; oC[o] = jc;                                 \
      if (t == 2) x2s = jc * invh;                                          \
      if (t == 3) x3s = jc * invh;                                          \
    }                                                                       \
    dxe = x3s - x2s; xe = x3s;                                              \
  }

// ---------------- kernel 2: per-lane sequential simulation ----------------
__global__ __launch_bounds__(64, 1) void simulate(
    const float* __restrict__ Cv, const float* __restrict__ K,
    const float* __restrict__ jmin, const float2* __restrict__ tbl,
    float* __restrict__ out) {
    __shared__ float2 stbl[TBL_N];    // 64 KB
    const int l = threadIdx.x;
    for (int i = l; i < TBL_N / 2; i += 64)
        reinterpret_cast<float4*>(stbl)[i] =
            reinterpret_cast<const float4*>(tbl)[i];
    __syncthreads();

    const int b = blockIdx.x * 64 + l;
    const float cv = Cv[b];
    const float kk = K[b];
    const float jm = jmin[b];
    const float Qmin = 3.3068376f * powf(kk, 1.3333334f);
    const float cvDT = cv * 0.1f;
    const float invh = (float)TBL_N / JMAX;

    float* __restrict__ oT = out + (size_t)b * NT;
    float* __restrict__ oR = out + (size_t)BATCH * NT + (size_t)b * NT;
    float* __restrict__ oC = out + 2 * (size_t)BATCH * NT + (size_t)b * NT;

    // ---- Phase A: find crossing step n_c (Q strictly increasing) ----
    int nc = 1 << 20;
    {
        float Q = 0.0f;
        for (int o = 1; o <= 360; ++o) {
            float BC = 0.1f * (float)o;
            float jc = (0.14f * BC) * 0.125f;   // res == 50 exactly pre-cross
            Q = fmaf(jc, 0.1f, Q);
            if (Q > Qmin) { nc = o; break; }
        }
        nc = min(nc, NT - 1);
    }
    int nmin = nc, nmax = nc;
#pragma unroll
    for (int m = 32; m >= 1; m >>= 1) {
        nmin = min(nmin, __shfl_xor(nmin, m, 64));
        nmax = max(nmax, __shfl_xor(nmax, m, 64));
    }
    const int G  = (NT - nmin + 7) >> 3;     // 8-step iterations
    const int o0 = NT - 8 * G;               // first simulated step (mult of 8)
    const int Gg = (nmax - o0 + 7) >> 3;     // iterations needing the gate

    // ---- Phase B: closed-form fill for o in [0, o0) ----
    for (int k = 0; k < (o0 >> 2); ++k) {
        int o = 4 * k;
        float4 jv;
        jv.x = (o == 0) ? 1e-3f : (0.14f * (0.1f * (float)o)) * 0.125f;
        jv.y = (0.14f * (0.1f * (float)(o + 1))) * 0.125f;
        jv.z = (0.14f * (0.1f * (float)(o + 2))) * 0.125f;
        jv.w = (0.14f * (0.1f * (float)(o + 3))) * 0.125f;
        reinterpret_cast<float4*>(oT)[k] = make_float4(0.f, 0.f, 0.f, 0.f);
        reinterpret_cast<float4*>(oR)[k] = make_float4(50.f, 50.f, 50.f, 50.f);
        reinterpret_cast<float4*>(oC)[k] = jv;
    }

    // ---- Phase C: pipelined sequential simulation from o0 ----
    float res = 50.0f, thk = 0.0f;

    float Av[4], Ad[4], Af[4], Bv[4], Bd[4], Bf[4];
#pragma unroll
    for (int t = 0; t < 4; ++t) {            // analytic prefill (res==50 here)
        float x = ((0.14f * (0.1f * (float)(o0 + t))) * 0.125f) * invh;
        int ip = (int)x;
        Af[t] = x - (float)ip;
        float2 vd = stbl[ip];
        Av[t] = vd.x; Ad[t] = vd.y;
    }
    float xe  = ((0.14f * (0.1f * (float)(o0 - 1))) * 0.125f) * invh;
    float dxe = xe - ((0.14f * (0.1f * (float)(o0 - 2))) * 0.125f) * invh;

    int ob = o0;
    for (int i = 0; i < Gg; ++i) {
        HALF(Av, Ad, Af, Bv, Bd, Bf, true, ob);
        HALF(Bv, Bd, Bf, Av, Ad, Af, true, (ob + 4));
        ob += 8;
    }
    for (int i = Gg; i < G; ++i) {
        HALF(Av, Ad, Af, Bv, Bd, Bf, false, ob);
        HALF(Bv, Bd, Bf, Av, Ad, Af, false, (ob + 4));
        ob += 8;
    }
}

extern "C" void kernel_launch(void* const* d_in, const int* in_sizes, int n_in,
                              void* d_out, int out_size, void* d_ws, size_t ws_size,
                              hipStream_t stream) {
    const float* Cv   = (const float*)d_in[0];
    const float* K    = (const float*)d_in[1];
    const float* jmin = (const float*)d_in[2];
    const float* W1   = (const float*)d_in[3];
    const float* b1   = (const float*)d_in[4];
    const float* W2   = (const float*)d_in[5];
    const float* b2   = (const float*)d_in[6];
    const float* W3   = (const float*)d_in[7];
    const float* b3   = (const float*)d_in[8];
    float* out = (float*)d_out;
    float2* tbl = (float2*)d_ws;   // TBL_N float2 = 64 KB scratch

    const int fill_blocks = (BATCH * NT / 4) / 256;   // 8000
    prep<<<TBLOCKS + fill_blocks, 256, 0, stream>>>(W1, b1, W2, b2, W3, b3, tbl, out);
    simulate<<<BATCH / 64, 64, 0, stream>>>(Cv, K, jmin, tbl, out);
}

// Round 6
// 210.930 us; speedup vs baseline: 1.1371x; 1.0624x over previous
//
#include <hip/hip_runtime.h>

#define NT      2000
#define BATCH   4096
#define NODES   64
#define TBL_N   8192
#define JMAX    3.6f
#define TBLOCKS (TBL_N / 256)

// ---------------- MLP evaluation helper (build phase only) ----------------
__device__ __forceinline__ float mlp_rho(float j,
    const float* sW1, const float* sB1, const float* sW2,
    const float* sB2, const float* sW3, float b3v) {
    float h1[NODES];
#pragma unroll
    for (int k = 0; k < NODES; ++k)
        h1[k] = fmaxf(fmaf(j, sW1[k], sB1[k]), 0.0f);
    float rho = b3v;
    for (int nt = 0; nt < NODES; nt += 8) {
        float acc[8];
#pragma unroll
        for (int q = 0; q < 8; ++q) acc[q] = sB2[nt + q];
#pragma unroll
        for (int k = 0; k < NODES; ++k) {
            float a = h1[k];
#pragma unroll
            for (int q = 0; q < 8; ++q)
                acc[q] = fmaf(a, sW2[k * NODES + nt + q], acc[q]);
        }
#pragma unroll
        for (int q = 0; q < 8; ++q)
            rho = fmaf(fmaxf(acc[q], 0.0f), sW3[nt + q], rho);
    }
    return rho;
}

// ------ kernel 1: blocks [0,32) build rho table; rest fill time plane ------
__global__ __launch_bounds__(256) void prep(
    const float* __restrict__ W1, const float* __restrict__ b1,
    const float* __restrict__ W2, const float* __restrict__ b2,
    const float* __restrict__ W3, const float* __restrict__ b3,
    float2* __restrict__ tbl, float* __restrict__ out) {
    __shared__ float sW2[NODES * NODES];
    __shared__ float sW1[NODES], sB1[NODES], sB2[NODES], sW3[NODES];
    __shared__ float sB3;

    if (blockIdx.x < TBLOCKS) {
        for (int i = threadIdx.x; i < NODES * NODES; i += 256) sW2[i] = W2[i];
        if (threadIdx.x < NODES) {
            sW1[threadIdx.x] = W1[threadIdx.x];
            sB1[threadIdx.x] = b1[threadIdx.x];
            sB2[threadIdx.x] = b2[threadIdx.x];
            sW3[threadIdx.x] = W3[threadIdx.x];
        }
        if (threadIdx.x == 0) sB3 = b3[0];
        __syncthreads();

        int idx = blockIdx.x * 256 + threadIdx.x;
        const float h = JMAX / (float)TBL_N;
        float j0 = h * (float)idx;
        float v0 = mlp_rho(j0,     sW1, sB1, sW2, sB2, sW3, sB3);
        float v1 = mlp_rho(j0 + h, sW1, sB1, sW2, sB2, sW3, sB3);
        tbl[idx] = make_float2(v0, v1 - v0);
    } else {
        int e = (blockIdx.x - TBLOCKS) * 256 + threadIdx.x;   // float4 index
        int t0 = (e * 4) % NT;                                // NT % 4 == 0
        float4 v = make_float4(0.1f * (float)t0, 0.1f * (float)(t0 + 1),
                               0.1f * (float)(t0 + 2), 0.1f * (float)(t0 + 3));
        reinterpret_cast<float4*>(out + 3 * (size_t)BATCH * NT)[e] = v;
    }
}

// one 4-step half: issue prefetch for steps OB+4..OB+7 into bank B,
// consume bank A for steps OB..OB+3. Stores only when DOST (wave-uniform).
#define HALF(AV, AD, AF, BV, BD, BF, GATED, OB, DOST)                       \
  {                                                                         \
    _Pragma("unroll")                                                       \
    for (int t = 0; t < 4; ++t) {                                           \
      float p = fmaf((float)(t + 5), dxe, xe);                              \
      p = fminf(fmaxf(p, 0.0f), (float)(TBL_N - 2));                        \
      int ip = (int)p;                                                      \
      BF[t] = p - (float)ip;                                                \
      float2 vd = stbl[ip];                                                 \
      BV[t] = vd.x; BD[t] = vd.y;                                           \
    }                                                                       \
    float x2s = 0.0f, x3s = 0.0f;                                           \
    _Pragma("unroll")                                                       \
    for (int t = 0; t < 4; ++t) {                                           \
      int o = (OB) + t;                                                     \
      float BC  = 0.1f * (float)o;                                          \
      float den = fmaf(0.14f, res, 1.0f);                                   \
      float jc  = (0.14f * BC) * __builtin_amdgcn_rcpf(den);                \
      float rho = fmaf(AF[t], AD[t], AV[t]);                                \
      float d1  = jc - jm;                                                  \
      float tn  = fmaxf(fmaf(d1, cvDT, thk), 0.0f);                         \
      float rn  = fmaxf(fmaf(d1, rho * cvDT, res), 50.0f);                  \
      if (GATED) {                                                          \
        bool g = (o >= nc);                                                 \
        thk = g ? tn : thk;  res = g ? rn : res;                            \
      } else { thk = tn; res = rn; }                                        \
      if (DOST) { oT[o] = thk; oR[o] = res; oC[o] = jc; }                   \
      if (t == 2) x2s = jc * invh;                                          \
      if (t == 3) x3s = jc * invh;                                          \
    }                                                                       \
    dxe = x3s - x2s; xe = x3s;                                              \
  }

// ---------------- kernel 2: per-lane sequential simulation ----------------
// 4 sibling blocks per 64-chain group run the identical recurrence;
// block (blockIdx&3)==w stores only iterations with (i&3)==w.
__global__ __launch_bounds__(64, 1) void simulate(
    const float* __restrict__ Cv, const float* __restrict__ K,
    const float* __restrict__ jmin, const float2* __restrict__ tbl,
    float* __restrict__ out) {
    __shared__ float2 stbl[TBL_N];    // 64 KB
    const int l = threadIdx.x;
    for (int i = l; i < TBL_N / 2; i += 64)
        reinterpret_cast<float4*>(stbl)[i] =
            reinterpret_cast<const float4*>(tbl)[i];
    __syncthreads();

    const int grp = blockIdx.x >> 2;
    const int w   = blockIdx.x & 3;
    const int b   = grp * 64 + l;
    const float cv = Cv[b];
    const float kk = K[b];
    const float jm = jmin[b];
    const float Qmin = 3.3068376f * powf(kk, 1.3333334f);
    const float cvDT = cv * 0.1f;
    const float invh = (float)TBL_N / JMAX;

    float* __restrict__ oT = out + (size_t)b * NT;
    float* __restrict__ oR = out + (size_t)BATCH * NT + (size_t)b * NT;
    float* __restrict__ oC = out + 2 * (size_t)BATCH * NT + (size_t)b * NT;

    // ---- Phase A: find crossing step n_c (identical in all 4 siblings) ----
    int nc = 1 << 20;
    {
        float Q = 0.0f;
        for (int o = 1; o <= 360; ++o) {
            float BC = 0.1f * (float)o;
            float jc = (0.14f * BC) * 0.125f;   // res == 50 exactly pre-cross
            Q = fmaf(jc, 0.1f, Q);
            if (Q > Qmin) { nc = o; break; }
        }
        nc = min(nc, NT - 1);
    }
    int nmin = nc, nmax = nc;
#pragma unroll
    for (int m = 32; m >= 1; m >>= 1) {
        nmin = min(nmin, __shfl_xor(nmin, m, 64));
        nmax = max(nmax, __shfl_xor(nmax, m, 64));
    }
    const int G  = (NT - nmin + 7) >> 3;     // 8-step iterations
    const int o0 = NT - 8 * G;               // first simulated step (mult of 8)
    const int Gg = (nmax - o0 + 7) >> 3;     // iterations needing the gate

    // ---- Phase B: closed-form fill for o in [0, o0), split across siblings ----
    for (int k = w; k < (o0 >> 2); k += 4) {
        int o = 4 * k;
        float4 jv;
        jv.x = (o == 0) ? 1e-3f : (0.14f * (0.1f * (float)o)) * 0.125f;
        jv.y = (0.14f * (0.1f * (float)(o + 1))) * 0.125f;
        jv.z = (0.14f * (0.1f * (float)(o + 2))) * 0.125f;
        jv.w = (0.14f * (0.1f * (float)(o + 3))) * 0.125f;
        reinterpret_cast<float4*>(oT)[k] = make_float4(0.f, 0.f, 0.f, 0.f);
        reinterpret_cast<float4*>(oR)[k] = make_float4(50.f, 50.f, 50.f, 50.f);
        reinterpret_cast<float4*>(oC)[k] = jv;
    }

    // ---- Phase C: pipelined sequential simulation from o0 ----
    float res = 50.0f, thk = 0.0f;

    float Av[4], Ad[4], Af[4], Bv[4], Bd[4], Bf[4];
#pragma unroll
    for (int t = 0; t < 4; ++t) {            // analytic prefill (res==50 here)
        float x = ((0.14f * (0.1f * (float)(o0 + t))) * 0.125f) * invh;
        int ip = (int)x;
        Af[t] = x - (float)ip;
        float2 vd = stbl[ip];
        Av[t] = vd.x; Ad[t] = vd.y;
    }
    float xe  = ((0.14f * (0.1f * (float)(o0 - 1))) * 0.125f) * invh;
    float dxe = xe - ((0.14f * (0.1f * (float)(o0 - 2))) * 0.125f) * invh;

    int ob = o0;
    for (int i = 0; i < Gg; ++i) {
        const bool st = ((i & 3) == w);
        HALF(Av, Ad, Af, Bv, Bd, Bf, true, ob, st);
        HALF(Bv, Bd, Bf, Av, Ad, Af, true, (ob + 4), st);
        ob += 8;
    }
    for (int i = Gg; i < G; ++i) {
        const bool st = ((i & 3) == w);
        HALF(Av, Ad, Af, Bv, Bd, Bf, false, ob, st);
        HALF(Bv, Bd, Bf, Av, Ad, Af, false, (ob + 4), st);
        ob += 8;
    }
}

extern "C" void kernel_launch(void* const* d_in, const int* in_sizes, int n_in,
                              void* d_out, int out_size, void* d_ws, size_t ws_size,
                              hipStream_t stream) {
    const float* Cv   = (const float*)d_in[0];
    const float* K    = (const float*)d_in[1];
    const float* jmin = (const float*)d_in[2];
    const float* W1   = (const float*)d_in[3];
    const float* b1   = (const float*)d_in[4];
    const float* W2   = (const float*)d_in[5];
    const float* b2   = (const float*)d_in[6];
    const float* W3   = (const float*)d_in[7];
    const float* b3   = (const float*)d_in[8];
    float* out = (float*)d_out;
    float2* tbl = (float2*)d_ws;   // TBL_N float2 = 64 KB scratch

    const int fill_blocks = (BATCH * NT / 4) / 256;   // 8000
    prep<<<TBLOCKS + fill_blocks, 256, 0, stream>>>(W1, b1, W2, b2, W3, b3, tbl, out);
    simulate<<<(BATCH / 64) * 4, 64, 0, stream>>>(Cv, K, jmin, tbl, out);
}

// Round 7
// 204.860 us; speedup vs baseline: 1.1708x; 1.0296x over previous
//
#include <hip/hip_runtime.h>

#define NT      2000
#define BATCH   4096
#define NODES   64
#define TBL_N   8192
#define JMAX    3.6f
#define TBLOCKS (TBL_N / 256)

// ---------------- MLP evaluation helper (build phase only) ----------------
__device__ __forceinline__ float mlp_rho(float j,
    const float* sW1, const float* sB1, const float* sW2,
    const float* sB2, const float* sW3, float b3v) {
    float h1[NODES];
#pragma unroll
    for (int k = 0; k < NODES; ++k)
        h1[k] = fmaxf(fmaf(j, sW1[k], sB1[k]), 0.0f);
    float rho = b3v;
    for (int nt = 0; nt < NODES; nt += 8) {
        float acc[8];
#pragma unroll
        for (int q = 0; q < 8; ++q) acc[q] = sB2[nt + q];
#pragma unroll
        for (int k = 0; k < NODES; ++k) {
            float a = h1[k];
#pragma unroll
            for (int q = 0; q < 8; ++q)
                acc[q] = fmaf(a, sW2[k * NODES + nt + q], acc[q]);
        }
#pragma unroll
        for (int q = 0; q < 8; ++q)
            rho = fmaf(fmaxf(acc[q], 0.0f), sW3[nt + q], rho);
    }
    return rho;
}

// ------ kernel 1: blocks [0,32) build rho table; rest fill time plane ------
__global__ __launch_bounds__(256) void prep(
    const float* __restrict__ W1, const float* __restrict__ b1,
    const float* __restrict__ W2, const float* __restrict__ b2,
    const float* __restrict__ W3, const float* __restrict__ b3,
    float2* __restrict__ tbl, float* __restrict__ out) {
    __shared__ float sW2[NODES * NODES];
    __shared__ float sW1[NODES], sB1[NODES], sB2[NODES], sW3[NODES];
    __shared__ float sB3;

    if (blockIdx.x < TBLOCKS) {
        for (int i = threadIdx.x; i < NODES * NODES; i += 256) sW2[i] = W2[i];
        if (threadIdx.x < NODES) {
            sW1[threadIdx.x] = W1[threadIdx.x];
            sB1[threadIdx.x] = b1[threadIdx.x];
            sB2[threadIdx.x] = b2[threadIdx.x];
            sW3[threadIdx.x] = W3[threadIdx.x];
        }
        if (threadIdx.x == 0) sB3 = b3[0];
        __syncthreads();

        int idx = blockIdx.x * 256 + threadIdx.x;
        const float h = JMAX / (float)TBL_N;
        float j0 = h * (float)idx;
        float v0 = mlp_rho(j0,     sW1, sB1, sW2, sB2, sW3, sB3);
        float v1 = mlp_rho(j0 + h, sW1, sB1, sW2, sB2, sW3, sB3);
        tbl[idx] = make_float2(v0, v1 - v0);
    } else {
        int e = (blockIdx.x - TBLOCKS) * 256 + threadIdx.x;   // float4 index
        int t0 = (e * 4) % NT;                                // NT % 4 == 0
        float4 v = make_float4(0.1f * (float)t0, 0.1f * (float)(t0 + 1),
                               0.1f * (float)(t0 + 2), 0.1f * (float)(t0 + 3));
        reinterpret_cast<float4*>(out + 3 * (size_t)BATCH * NT)[e] = v;
    }
}

// one 4-step half: prefetch rho for OB+4..OB+7 into bank B, consume bank A.
#define HALF(AV, AD, AF, BV, BD, BF, GATED, OB)                             \
  {                                                                         \
    _Pragma("unroll")                                                       \
    for (int t = 0; t < 4; ++t) {                                           \
      float p = fmaf((float)(t + 5), dxe, xe);                              \
      p = fminf(fmaxf(p, 0.0f), (float)(TBL_N - 2));                        \
      int ip = (int)p;                                                      \
      BF[t] = p - (float)ip;                                                \
      float2 vd = stbl[ip];                                                 \
      BV[t] = vd.x; BD[t] = vd.y;                                           \
    }                                                                       \
    float x2s = 0.0f, x3s = 0.0f;                                           \
    _Pragma("unroll")                                                       \
    for (int t = 0; t < 4; ++t) {                                           \
      int o = (OB) + t;                                                     \
      float BC  = 0.1f * (float)o;                                          \
      float den = fmaf(0.14f, res, 1.0f);                                   \
      float jc  = (0.14f * BC) * __builtin_amdgcn_rcpf(den);                \
      float rho = fmaf(AF[t], AD[t], AV[t]);                                \
      float d1  = jc - jm;                                                  \
      float rn  = fmaxf(fmaf(d1, rho * cvDT, res), 50.0f);                  \
      if (GATED) { res = (o >= nc) ? rn : res; } else { res = rn; }         \
      oR[o] = res;                                                          \
      if (t == 2) x2s = jc * invh;                                          \
      if (t == 3) x3s = jc * invh;                                          \
    }                                                                       \
    dxe = x3s - x2s; xe = x3s;                                              \
  }

// ---------------- kernel 2: sequential res recurrence only ----------------
__global__ __launch_bounds__(64, 1) void res_chain(
    const float* __restrict__ Cv, const float* __restrict__ K,
    const float* __restrict__ jmin, const float2* __restrict__ tbl,
    int* __restrict__ ncArr, float* __restrict__ out) {
    __shared__ float2 stbl[TBL_N];    // 64 KB
    const int l = threadIdx.x;
    for (int i = l; i < TBL_N / 2; i += 64)
        reinterpret_cast<float4*>(stbl)[i] =
            reinterpret_cast<const float4*>(tbl)[i];
    __syncthreads();

    const int b = blockIdx.x * 64 + l;
    const float cv = Cv[b];
    const float kk = K[b];
    const float jm = jmin[b];
    const float Qmin = 3.3068376f * powf(kk, 1.3333334f);
    const float cvDT = cv * 0.1f;
    const float invh = (float)TBL_N / JMAX;

    float* __restrict__ oR = out + (size_t)BATCH * NT + (size_t)b * NT;

    // ---- Phase A: crossing step n_c (Q strictly increasing pre-cross) ----
    int nc = 1 << 20;
    {
        float Q = 0.0f;
        for (int o = 1; o <= 360; ++o) {
            float BC = 0.1f * (float)o;
            float jc = (0.14f * BC) * 0.125f;   // res == 50 exactly pre-cross
            Q = fmaf(jc, 0.1f, Q);
            if (Q > Qmin) { nc = o; break; }
        }
        nc = min(nc, NT - 1);
    }
    ncArr[b] = nc;
    int nmin = nc, nmax = nc;
#pragma unroll
    for (int m = 32; m >= 1; m >>= 1) {
        nmin = min(nmin, __shfl_xor(nmin, m, 64));
        nmax = max(nmax, __shfl_xor(nmax, m, 64));
    }
    const int G  = (NT - nmin + 7) >> 3;
    const int o0 = NT - 8 * G;
    const int Gg = (nmax - o0 + 7) >> 3;

    // ---- fill res = 50 for o in [0, o0) ----
    for (int k = 0; k < (o0 >> 2); ++k)
        reinterpret_cast<float4*>(oR)[k] = make_float4(50.f, 50.f, 50.f, 50.f);

    // ---- pipelined sequential recurrence from o0 ----
    float res = 50.0f;
    float Av[4], Ad[4], Af[4], Bv[4], Bd[4], Bf[4];
#pragma unroll
    for (int t = 0; t < 4; ++t) {
        float x = ((0.14f * (0.1f * (float)(o0 + t))) * 0.125f) * invh;
        int ip = (int)x;
        Af[t] = x - (float)ip;
        float2 vd = stbl[ip];
        Av[t] = vd.x; Ad[t] = vd.y;
    }
    float xe  = ((0.14f * (0.1f * (float)(o0 - 1))) * 0.125f) * invh;
    float dxe = xe - ((0.14f * (0.1f * (float)(o0 - 2))) * 0.125f) * invh;

    int ob = o0;
    for (int i = 0; i < Gg; ++i) {
        HALF(Av, Ad, Af, Bv, Bd, Bf, true, ob);
        HALF(Bv, Bd, Bf, Av, Ad, Af, true, (ob + 4));
        ob += 8;
    }
    for (int i = Gg; i < G; ++i) {
        HALF(Av, Ad, Af, Bv, Bd, Bf, false, ob);
        HALF(Bv, Bd, Bf, Av, Ad, Af, false, (ob + 4));
        ob += 8;
    }
}

// ---------------- kernel 3: parallel expansion (j, thk) ----------------
// One wave per chain; thk via clamped-prefix (S,C) scan:
//   step map (active): y -> max(y + d, 0)  == (S=d, C=0)
//   identity:          y -> y              == (S=0, C=-inf)
//   compose f1 then f2: S = S1+S2, C = max(C1+S2, C2)
__global__ __launch_bounds__(256) void expand(
    const float* __restrict__ Cv, const float* __restrict__ jmin,
    const int* __restrict__ ncArr, float* __restrict__ out) {
    const int lane = threadIdx.x & 63;
    const int b = blockIdx.x * 4 + (threadIdx.x >> 6);

    const float cv = Cv[b];
    const float jm = jmin[b];
    const float cvDT = cv * 0.1f;
    const int   nc = ncArr[b];

    const float* __restrict__ R = out + (size_t)BATCH * NT + (size_t)b * NT;
    float* __restrict__ T = out + (size_t)b * NT;
    float* __restrict__ C = out + 2 * (size_t)BATCH * NT + (size_t)b * NT;

    float y = 0.0f;          // thk state entering the chunk
    float carry_res = 50.0f; // res[last lane of previous chunk]

    for (int k = 0; k < (NT + 63) / 64; ++k) {
        const int o = 64 * k + lane;
        const int ol = min(o, NT - 1);
        float rv = R[ol];

        float resp = __shfl_up(rv, 1, 64);
        if (lane == 0) resp = carry_res;
        carry_res = __shfl(rv, 63, 64);

        float BC = 0.1f * (float)o;
        float j = (0.14f * BC) * __builtin_amdgcn_rcpf(fmaf(0.14f, resp, 1.0f));
        if (o == 0) j = 1e-3f;

        const bool active = (o >= nc);
        float S  = active ? cvDT * (j - jm) : 0.0f;
        float Cq = active ? 0.0f : -1e30f;

#pragma unroll
        for (int m = 1; m < 64; m <<= 1) {
            float Su = __shfl_up(S, m, 64);
            float Cu = __shfl_up(Cq, m, 64);
            if (lane >= m) {
                Cq = fmaxf(Cu + S, Cq);   // uses pre-update S (mine)
                S  = Su + S;
            }
        }
        float thk = fmaxf(y + S, Cq);
        y = __shfl(thk, 63, 64);

        if (o < NT) {
            T[o] = thk;
            C[o] = j;
        }
    }
}

extern "C" void kernel_launch(void* const* d_in, const int* in_sizes, int n_in,
                              void* d_out, int out_size, void* d_ws, size_t ws_size,
                              hipStream_t stream) {
    const float* Cv   = (const float*)d_in[0];
    const float* K    = (const float*)d_in[1];
    const float* jmin = (const float*)d_in[2];
    const float* W1   = (const float*)d_in[3];
    const float* b1   = (const float*)d_in[4];
    const float* W2   = (const float*)d_in[5];
    const float* b2   = (const float*)d_in[6];
    const float* W3   = (const float*)d_in[7];
    const float* b3   = (const float*)d_in[8];
    float* out = (float*)d_out;
    float2* tbl  = (float2*)d_ws;                               // 64 KB
    int*    ncA  = (int*)((char*)d_ws + TBL_N * sizeof(float2)); // 16 KB

    const int fill_blocks = (BATCH * NT / 4) / 256;   // 8000
    prep<<<TBLOCKS + fill_blocks, 256, 0, stream>>>(W1, b1, W2, b2, W3, b3, tbl, out);
    res_chain<<<BATCH / 64, 64, 0, stream>>>(Cv, K, jmin, tbl, ncA, out);
    expand<<<BATCH / 4, 256, 0, stream>>>(Cv, jmin, ncA, out);
}